// Round 2
// baseline (325.379 us; speedup 1.0000x reference)
//
#include <hip/hip_runtime.h>
#include <hip/hip_bf16.h>

// Problem constants (CrossEncoder): B=4, QT=1024, N=2048, E=512, H=8, Dh=64
#define B_  4
#define QT_ 1024
#define N_  2048
#define E_  512
#define H_  8
#define DH_ 64

typedef float  f32x4  __attribute__((ext_vector_type(4)));
typedef __bf16 bf16x8 __attribute__((ext_vector_type(8)));
typedef unsigned short u16;
typedef u16 u16x8 __attribute__((ext_vector_type(8)));
typedef u16 u16x4 __attribute__((ext_vector_type(4)));

// round-to-nearest-even f32 -> bf16
static __device__ __forceinline__ u16 f2bf(float f) {
    unsigned u = __builtin_bit_cast(unsigned, f);
    return (u16)((u + 0x7fffu + ((u >> 16) & 1u)) >> 16);
}

static __device__ __forceinline__ bf16x8 ldbf8(const u16* p) {
    uint4 v = *reinterpret_cast<const uint4*>(p);
    return __builtin_bit_cast(bf16x8, v);
}

#define MFMA16(a, b, c) __builtin_amdgcn_mfma_f32_16x16x32_bf16((a), (b), (c), 0, 0, 0)

// -------------------- f32 -> bf16 convert (vectorized) --------------------
__global__ __launch_bounds__(256) void cvt_f32_bf16(const float* __restrict__ s,
                                                    u16* __restrict__ d, int n4) {
    int i = blockIdx.x * 256 + threadIdx.x;
    if (i >= n4) return;
    float4 v = reinterpret_cast<const float4*>(s)[i];
    ushort4 o;
    o.x = f2bf(v.x); o.y = f2bf(v.y); o.z = f2bf(v.z); o.w = f2bf(v.w);
    reinterpret_cast<ushort4*>(d)[i] = o;
}

// -------------------- weight transpose + convert: Wt[n][k] = bf16(W[k][n]) --------------------
__global__ __launch_bounds__(256) void w_transpose(const float* __restrict__ W,
                                                   u16* __restrict__ Wt) {
    __shared__ float t[64][65];
    int k0 = blockIdx.x * 64, n0 = blockIdx.y * 64;
    int tid = threadIdx.x;
#pragma unroll
    for (int i = 0; i < 16; i++) {
        int idx = tid + i * 256, r = idx >> 6, c = idx & 63;
        t[r][c] = W[(k0 + r) * E_ + n0 + c];
    }
    __syncthreads();
#pragma unroll
    for (int i = 0; i < 16; i++) {
        int idx = tid + i * 256, r = idx >> 6, c = idx & 63;
        Wt[(n0 + r) * E_ + k0 + c] = f2bf(t[c][r]);
    }
}

// -------------------- RoPE table: tab[row*16 + k] = (cos, sin)(pos[row] * 10000^(-k/32)) ----
// Reference quirk: cos/sin are repeat(2)'d THEN sliced [:32] -> pair i uses freq idx d>>2.
__global__ __launch_bounds__(256) void rope_table(const int* __restrict__ pos,
                                                  float2* __restrict__ tab, int rows) {
    int i = blockIdx.x * 256 + threadIdx.x;
    if (i >= rows * 16) return;
    int k = i & 15, row = i >> 4;
    float fr = exp2f((float)k * -0.41524101186092028f);  // log2(10000)/32
    float ang = (float)pos[row] * fr;
    float sn, cs;
    sincosf(ang, &sn, &cs);
    tab[i] = make_float2(cs, sn);
}

// -------------------- projection GEMM: out[M,512] = X[M,512] @ W + b --------------------
// MODE 0: fused RoPE epilogue, write bf16 head layout [B,H,SEQ,64]
// MODE 1: write bf16 row-major [M,512]   (V)
// MODE 2: write f32 row-major, * q_mask  (O, into d_out)
template <int MODE, int SEQ>
__global__ __launch_bounds__(256) void proj_gemm(const u16* __restrict__ X,
                                                 const u16* __restrict__ Wt,
                                                 const float* __restrict__ bias,
                                                 void* __restrict__ outp,
                                                 const float2* __restrict__ rope_tab,
                                                 const int* __restrict__ qmask) {
    const int m0 = blockIdx.x * 128, n0 = blockIdx.y * 128;
    const int tid = threadIdx.x;
    const int w = tid >> 6, lane = tid & 63;
    const int lr = lane & 15, lg = lane >> 4;
    const int wm = m0 + (w >> 1) * 64, wn = n0 + (w & 1) * 64;

    f32x4 acc[4][4];
#pragma unroll
    for (int i = 0; i < 4; i++)
#pragma unroll
        for (int j = 0; j < 4; j++) acc[i][j] = f32x4{0.f, 0.f, 0.f, 0.f};

    for (int ks = 0; ks < 16; ks++) {
        const int ko = ks * 32 + lg * 8;
        bf16x8 a[4], bb[4];
#pragma unroll
        for (int mb = 0; mb < 4; mb++) a[mb] = ldbf8(X + (wm + mb * 16 + lr) * E_ + ko);
#pragma unroll
        for (int nb = 0; nb < 4; nb++) bb[nb] = ldbf8(Wt + (wn + nb * 16 + lr) * E_ + ko);
#pragma unroll
        for (int mb = 0; mb < 4; mb++)
#pragma unroll
            for (int nb = 0; nb < 4; nb++)
                acc[mb][nb] = MFMA16(a[mb], bb[nb], acc[mb][nb]);
    }

#pragma unroll
    for (int mb = 0; mb < 4; mb++) {
#pragma unroll
        for (int nb = 0; nb < 4; nb++) {
            const int col = wn + nb * 16 + lr;     // C col = lane&15
            const float bs = bias[col];
#pragma unroll
            for (int r = 0; r < 4; r++) {
                const int row = wm + mb * 16 + lg * 4 + r;  // C row = (lane>>4)*4 + reg
                float v = acc[mb][nb][r] + bs;
                if (MODE == 0) {
                    const int d = col & 63, h = col >> 6;
                    float2 t = rope_tab[row * 16 + (d >> 2)];
                    float other = __shfl_xor(v, 1);  // pair mate: col^1 lives in lane^1
                    float y = (d & 1) ? (other * t.y + v * t.x) : (v * t.x - other * t.y);
                    const int b = row / SEQ, tok = row % SEQ;
                    ((u16*)outp)[((b * H_ + h) * SEQ + tok) * DH_ + d] = f2bf(y);
                } else if (MODE == 1) {
                    ((u16*)outp)[row * E_ + col] = f2bf(v);
                } else {
                    float m = (qmask[row] != 0) ? 1.0f : 0.0f;
                    ((float*)outp)[row * E_ + col] = v * m;
                }
            }
        }
    }
}

// -------------------- V transpose: vt[b,h,d,N] = vlin[b,n,h*64+d] --------------------
__global__ __launch_bounds__(256) void v_transpose(const u16* __restrict__ vlin,
                                                   u16* __restrict__ vt) {
    __shared__ u16 t[64][66];
    int bh = blockIdx.x, n0 = blockIdx.y * 64;
    int b = bh >> 3, h = bh & 7;
    int tid = threadIdx.x;
#pragma unroll
    for (int i = 0; i < 16; i++) {
        int idx = tid + i * 256, r = idx >> 6, c = idx & 63;  // r = n off, c = d
        t[r][c] = vlin[(b * N_ + n0 + r) * E_ + h * DH_ + c];
    }
    __syncthreads();
#pragma unroll
    for (int i = 0; i < 16; i++) {
        int idx = tid + i * 256, r = idx >> 6, c = idx & 63;  // r = d, c = n off
        vt[(bh * DH_ + r) * N_ + n0 + c] = t[c][r];
    }
}

// -------------------- fused attention (v2: N-split waves for occupancy) --------------------
// grid (QT/16, B*H), 256 thr. Each wg owns 16 q-rows; wave w owns kv cols [w*512, w*512+512).
// Max-free two-pass softmax (scores O(1), shift-invariant; masked -> exp underflows to 0 in
// the reference, so plain exp(s) matches). Pass A: partial row sums per wave, combined via
// LDS. Pass B: recompute scores, write normalized attn (nontemporal f32 - write-only, keep
// out of L2), accumulate partial PV per wave; combine PV across waves via reused P-tile LDS.
__global__ __launch_bounds__(256) void attn_kernel(const u16* __restrict__ qh,
                                                   const u16* __restrict__ kh,
                                                   const u16* __restrict__ vt,
                                                   const int* __restrict__ kv_mask,
                                                   float* __restrict__ attn_out,
                                                   u16* __restrict__ ctx_out) {
    __shared__ float plds[4][16][68];  // per-wave P tile [16 q][64 kv]; reused as PV-reduce buf
    __shared__ float sums[4][16];      // per-wave partial row sums
    const int q0 = blockIdx.x * 16, bh = blockIdx.y;
    const int b = bh >> 3, h = bh & 7;
    const int tid = threadIdx.x, w = tid >> 6, lane = tid & 63;
    const int lr = lane & 15, lg = lane >> 4;
    const int kv0 = w * 512;

    const u16* qbase = qh + (bh * QT_ + q0) * DH_;
    const bf16x8 qf0 = ldbf8(qbase + lr * DH_ + lg * 8);
    const bf16x8 qf1 = ldbf8(qbase + lr * DH_ + 32 + lg * 8);
    const u16* kbase = kh + bh * (N_ * DH_);
    const int* mbase = kv_mask + b * N_;

    // ---- pass A: partial row sums of exp(score) over this wave's kv slice ----
    float lsum[4] = {0.f, 0.f, 0.f, 0.f};
    for (int t = 0; t < 8; t++) {
#pragma unroll
        for (int n = 0; n < 4; n++) {
            const int cb = kv0 + t * 64 + n * 16;
            bf16x8 k0 = ldbf8(kbase + (cb + lr) * DH_ + lg * 8);
            bf16x8 k1 = ldbf8(kbase + (cb + lr) * DH_ + 32 + lg * 8);
            f32x4 c = f32x4{0.f, 0.f, 0.f, 0.f};
            c = MFMA16(qf0, k0, c);
            c = MFMA16(qf1, k1, c);
            const bool keep = (mbase[cb + lr] != 0);
#pragma unroll
            for (int r = 0; r < 4; r++) lsum[r] += keep ? __expf(c[r] * 0.125f) : 0.f;
        }
    }
#pragma unroll
    for (int r = 0; r < 4; r++) {
        float s = lsum[r];
        s += __shfl_xor(s, 1); s += __shfl_xor(s, 2);
        s += __shfl_xor(s, 4); s += __shfl_xor(s, 8);
        if (lr == 0) sums[w][lg * 4 + r] = s;  // lanes 0,16,32,48 cover rows lg*4+r
    }
    __syncthreads();
    float inv[4];
#pragma unroll
    for (int r = 0; r < 4; r++) {
        const int row = lg * 4 + r;
        float ttl = sums[0][row] + sums[1][row] + sums[2][row] + sums[3][row];
        inv[r] = (ttl > 0.f) ? (1.0f / ttl) : 0.f;  // all-masked row -> attn = ctx = 0 (ref)
    }

    // ---- pass B: write attn, accumulate partial ctx ----
    f32x4 pv[4];
#pragma unroll
    for (int i = 0; i < 4; i++) pv[i] = f32x4{0.f, 0.f, 0.f, 0.f};
    float(*P)[68] = plds[w];
    const u16* vbase = vt + bh * (DH_ * N_);
    float* abase = attn_out + ((size_t)(bh * QT_ + q0)) * N_;
    const int srow = lane >> 2, scol = (lane & 3) * 4;

    for (int t = 0; t < 8; t++) {
#pragma unroll
        for (int n = 0; n < 4; n++) {
            const int cb = kv0 + t * 64 + n * 16;
            bf16x8 k0 = ldbf8(kbase + (cb + lr) * DH_ + lg * 8);
            bf16x8 k1 = ldbf8(kbase + (cb + lr) * DH_ + 32 + lg * 8);
            f32x4 c = f32x4{0.f, 0.f, 0.f, 0.f};
            c = MFMA16(qf0, k0, c);
            c = MFMA16(qf1, k1, c);
            const bool keep = (mbase[cb + lr] != 0);
#pragma unroll
            for (int r = 0; r < 4; r++) {
                float p = keep ? (__expf(c[r] * 0.125f) * inv[r]) : 0.f;
                P[lg * 4 + r][n * 16 + lr] = p;  // per-wave LDS tile
            }
        }
        // nontemporal coalesced f32x4 attn stores (write-only buffer, keep out of L2)
#pragma unroll
        for (int i = 0; i < 4; i++) {
            f32x4 vv = *reinterpret_cast<const f32x4*>(&P[srow][i * 16 + scol]);
            __builtin_nontemporal_store(
                vv, reinterpret_cast<f32x4*>(abase + (size_t)srow * N_ + kv0 + t * 64 + i * 16 + scol));
        }
        // PV: ctx[16q,64d] += P[16q,64kv] @ V[64kv,64d]  (A via LDS transpose-read)
#pragma unroll
        for (int ks = 0; ks < 2; ks++) {
            const float* ap = &P[lr][ks * 32 + lg * 8];
            f32x4 a0 = *reinterpret_cast<const f32x4*>(ap);
            f32x4 a1 = *reinterpret_cast<const f32x4*>(ap + 4);
            u16x8 u;
            u[0] = f2bf(a0[0]); u[1] = f2bf(a0[1]); u[2] = f2bf(a0[2]); u[3] = f2bf(a0[3]);
            u[4] = f2bf(a1[0]); u[5] = f2bf(a1[1]); u[6] = f2bf(a1[2]); u[7] = f2bf(a1[3]);
            bf16x8 af = __builtin_bit_cast(bf16x8, u);
#pragma unroll
            for (int nb = 0; nb < 4; nb++) {
                bf16x8 bv = ldbf8(vbase + (nb * 16 + lr) * N_ + kv0 + t * 64 + ks * 32 + lg * 8);
                pv[nb] = MFMA16(af, bv, pv[nb]);
            }
        }
    }

    // ---- combine partial PV across waves (reuse plds) ----
    // Each wave writes only its own plds[w] region; barrier; then block-wide reduce.
#pragma unroll
    for (int nb = 0; nb < 4; nb++)
#pragma unroll
        for (int r = 0; r < 4; r++) plds[w][lg * 4 + r][nb * 16 + lr] = pv[nb][r];
    __syncthreads();

    // 1024 ctx elements (16 rows x 64 d), 4 per thread
    {
        const int row = tid >> 4, c4 = (tid & 15) * 4;
        u16x4 o;
#pragma unroll
        for (int j = 0; j < 4; j++) {
            float s = plds[0][row][c4 + j] + plds[1][row][c4 + j] +
                      plds[2][row][c4 + j] + plds[3][row][c4 + j];
            o[j] = f2bf(s);
        }
        // ctx layout [B, QT, H*64] bf16, feature = h*64+d
        *reinterpret_cast<u16x4*>(&ctx_out[((b * QT_ + q0 + row) * H_ + h) * DH_ + c4]) = o;
    }
}

// -------------------- host launch --------------------
extern "C" void kernel_launch(void* const* d_in, const int* in_sizes, int n_in,
                              void* d_out, int out_size, void* d_ws, size_t ws_size,
                              hipStream_t stream) {
    (void)in_sizes; (void)n_in; (void)out_size; (void)ws_size;
    const float* q   = (const float*)d_in[0];
    const float* kv  = (const float*)d_in[1];
    const int* q_mask  = (const int*)d_in[2];
    const int* kv_mask = (const int*)d_in[3];
    const int* q_pos   = (const int*)d_in[4];
    const int* kv_pos  = (const int*)d_in[5];
    const float* Wq = (const float*)d_in[6];  const float* bq = (const float*)d_in[7];
    const float* Wk = (const float*)d_in[8];  const float* bk = (const float*)d_in[9];
    const float* Wv = (const float*)d_in[10]; const float* bv = (const float*)d_in[11];
    const float* Wo = (const float*)d_in[12]; const float* bo = (const float*)d_in[13];
    float* outp = (float*)d_out;

    char* ws = (char*)d_ws;
    size_t off = 0;
    auto carve = [&](size_t bytes) -> void* {
        void* p = ws + off;
        off = (off + bytes + 255) & ~(size_t)255;
        return p;
    };
    u16* qbf   = (u16*)carve((size_t)B_ * QT_ * E_ * 2);
    u16* kvbf  = (u16*)carve((size_t)B_ * N_ * E_ * 2);
    u16* wtq   = (u16*)carve((size_t)E_ * E_ * 2);
    u16* wtk   = (u16*)carve((size_t)E_ * E_ * 2);
    u16* wtv   = (u16*)carve((size_t)E_ * E_ * 2);
    u16* wto   = (u16*)carve((size_t)E_ * E_ * 2);
    u16* qhh   = (u16*)carve((size_t)B_ * H_ * QT_ * DH_ * 2);
    u16* khh   = (u16*)carve((size_t)B_ * H_ * N_ * DH_ * 2);
    u16* vlin  = (u16*)carve((size_t)B_ * N_ * E_ * 2);
    u16* vt    = (u16*)carve((size_t)B_ * H_ * DH_ * N_ * 2);
    u16* ctx   = (u16*)carve((size_t)B_ * QT_ * E_ * 2);
    float2* tq = (float2*)carve((size_t)B_ * QT_ * 16 * sizeof(float2));
    float2* tk = (float2*)carve((size_t)B_ * N_ * 16 * sizeof(float2));

    cvt_f32_bf16<<<(B_ * QT_ * E_ / 4) / 256, 256, 0, stream>>>(q, qbf, B_ * QT_ * E_ / 4);
    cvt_f32_bf16<<<(B_ * N_ * E_ / 4) / 256, 256, 0, stream>>>(kv, kvbf, B_ * N_ * E_ / 4);
    w_transpose<<<dim3(8, 8), 256, 0, stream>>>(Wq, wtq);
    w_transpose<<<dim3(8, 8), 256, 0, stream>>>(Wk, wtk);
    w_transpose<<<dim3(8, 8), 256, 0, stream>>>(Wv, wtv);
    w_transpose<<<dim3(8, 8), 256, 0, stream>>>(Wo, wto);
    rope_table<<<(B_ * QT_ * 16) / 256, 256, 0, stream>>>(q_pos, tq, B_ * QT_);
    rope_table<<<(B_ * N_ * 16) / 256, 256, 0, stream>>>(kv_pos, tk, B_ * N_);

    proj_gemm<0, QT_><<<dim3(B_ * QT_ / 128, 4), 256, 0, stream>>>(qbf, wtq, bq, qhh, tq, nullptr);
    proj_gemm<0, N_><<<dim3(B_ * N_ / 128, 4), 256, 0, stream>>>(kvbf, wtk, bk, khh, tk, nullptr);
    proj_gemm<1, N_><<<dim3(B_ * N_ / 128, 4), 256, 0, stream>>>(kvbf, wtv, bv, vlin, nullptr, nullptr);
    v_transpose<<<dim3(B_ * H_, N_ / 64), 256, 0, stream>>>(vlin, vt);

    attn_kernel<<<dim3(QT_ / 16, B_ * H_), 256, 0, stream>>>(
        qhh, khh, vt, kv_mask, outp + (size_t)B_ * QT_ * E_, ctx);

    proj_gemm<2, QT_><<<dim3(B_ * QT_ / 128, 4), 256, 0, stream>>>(ctx, wto, bo, outp, nullptr, q_mask);
}

// Round 3
// 249.326 us; speedup vs baseline: 1.3050x; 1.3050x over previous
//
#include <hip/hip_runtime.h>
#include <hip/hip_bf16.h>

// Problem constants (CrossEncoder): B=4, QT=1024, N=2048, E=512, H=8, Dh=64
#define B_  4
#define QT_ 1024
#define N_  2048
#define E_  512
#define H_  8
#define DH_ 64

typedef float  f32x4  __attribute__((ext_vector_type(4)));
typedef __bf16 bf16x8 __attribute__((ext_vector_type(8)));
typedef unsigned short u16;
typedef u16 u16x8 __attribute__((ext_vector_type(8)));
typedef u16 u16x4 __attribute__((ext_vector_type(4)));

// round-to-nearest-even f32 -> bf16
static __device__ __forceinline__ u16 f2bf(float f) {
    unsigned u = __builtin_bit_cast(unsigned, f);
    return (u16)((u + 0x7fffu + ((u >> 16) & 1u)) >> 16);
}

static __device__ __forceinline__ bf16x8 ldbf8(const u16* p) {
    uint4 v = *reinterpret_cast<const uint4*>(p);
    return __builtin_bit_cast(bf16x8, v);
}

#define MFMA16(a, b, c) __builtin_amdgcn_mfma_f32_16x16x32_bf16((a), (b), (c), 0, 0, 0)

// async global->LDS, 16B per lane; LDS dest = uniform base + lane*16 (linear)
static __device__ __forceinline__ void g2lds16(const u16* g, u16* l) {
    __builtin_amdgcn_global_load_lds((__attribute__((address_space(1))) void*)(void*)g,
                                     (__attribute__((address_space(3))) void*)l, 16, 0, 0);
}

// -------------------- f32 -> bf16 convert (vectorized) --------------------
__global__ __launch_bounds__(256) void cvt_f32_bf16(const float* __restrict__ s,
                                                    u16* __restrict__ d, int n4) {
    int i = blockIdx.x * 256 + threadIdx.x;
    if (i >= n4) return;
    float4 v = reinterpret_cast<const float4*>(s)[i];
    ushort4 o;
    o.x = f2bf(v.x); o.y = f2bf(v.y); o.z = f2bf(v.z); o.w = f2bf(v.w);
    reinterpret_cast<ushort4*>(d)[i] = o;
}

// -------------------- weight transpose + convert: Wt[n][k] = bf16(W[k][n]) --------------------
__global__ __launch_bounds__(256) void w_transpose(const float* __restrict__ W,
                                                   u16* __restrict__ Wt) {
    __shared__ float t[64][65];
    int k0 = blockIdx.x * 64, n0 = blockIdx.y * 64;
    int tid = threadIdx.x;
#pragma unroll
    for (int i = 0; i < 16; i++) {
        int idx = tid + i * 256, r = idx >> 6, c = idx & 63;
        t[r][c] = W[(k0 + r) * E_ + n0 + c];
    }
    __syncthreads();
#pragma unroll
    for (int i = 0; i < 16; i++) {
        int idx = tid + i * 256, r = idx >> 6, c = idx & 63;
        Wt[(n0 + r) * E_ + k0 + c] = f2bf(t[c][r]);
    }
}

// -------------------- RoPE table (reference quirk: freq index = d>>2, 16 freqs) ----------
__global__ __launch_bounds__(256) void rope_table(const int* __restrict__ pos,
                                                  float2* __restrict__ tab, int rows) {
    int i = blockIdx.x * 256 + threadIdx.x;
    if (i >= rows * 16) return;
    int k = i & 15, row = i >> 4;
    float fr = exp2f((float)k * -0.41524101186092028f);  // log2(10000)/32
    float ang = (float)pos[row] * fr;
    float sn, cs;
    sincosf(ang, &sn, &cs);
    tab[i] = make_float2(cs, sn);
}

// -------------------- projection GEMM: 64x64 tile, wave = 32x32 --------------------
// MODE 0: fused RoPE epilogue, write bf16 head layout [B,H,SEQ,64]
// MODE 1: write bf16 V tiled layout [b*8+h][tile=n/64][d][64]
// MODE 2: write f32 row-major, * q_mask  (O, into d_out)
template <int MODE, int SEQ>
__global__ __launch_bounds__(256) void proj_gemm(const u16* __restrict__ X,
                                                 const u16* __restrict__ Wt,
                                                 const float* __restrict__ bias,
                                                 void* __restrict__ outp,
                                                 const float2* __restrict__ rope_tab,
                                                 const int* __restrict__ qmask) {
    const int m0 = blockIdx.x * 64, n0 = blockIdx.y * 64;
    const int tid = threadIdx.x;
    const int w = tid >> 6, lane = tid & 63;
    const int lr = lane & 15, lg = lane >> 4;
    const int wm = m0 + (w >> 1) * 32, wn = n0 + (w & 1) * 32;

    f32x4 acc[2][2];
#pragma unroll
    for (int i = 0; i < 2; i++)
#pragma unroll
        for (int j = 0; j < 2; j++) acc[i][j] = f32x4{0.f, 0.f, 0.f, 0.f};

    for (int ks = 0; ks < 16; ks++) {
        const int ko = ks * 32 + lg * 8;
        bf16x8 a[2], bb[2];
#pragma unroll
        for (int mb = 0; mb < 2; mb++) a[mb] = ldbf8(X + (wm + mb * 16 + lr) * E_ + ko);
#pragma unroll
        for (int nb = 0; nb < 2; nb++) bb[nb] = ldbf8(Wt + (wn + nb * 16 + lr) * E_ + ko);
#pragma unroll
        for (int mb = 0; mb < 2; mb++)
#pragma unroll
            for (int nb = 0; nb < 2; nb++)
                acc[mb][nb] = MFMA16(a[mb], bb[nb], acc[mb][nb]);
    }

#pragma unroll
    for (int mb = 0; mb < 2; mb++) {
#pragma unroll
        for (int nb = 0; nb < 2; nb++) {
            const int col = wn + nb * 16 + lr;     // C col = lane&15
            const float bs = bias[col];
#pragma unroll
            for (int r = 0; r < 4; r++) {
                const int row = wm + mb * 16 + lg * 4 + r;  // C row = (lane>>4)*4 + reg
                float v = acc[mb][nb][r] + bs;
                if (MODE == 0) {
                    const int d = col & 63, h = col >> 6;
                    float2 t = rope_tab[row * 16 + (d >> 2)];
                    float other = __shfl_xor(v, 1);  // pair mate: col^1 lives in lane^1
                    float y = (d & 1) ? (other * t.y + v * t.x) : (v * t.x - other * t.y);
                    const int b = row / SEQ, tok = row % SEQ;
                    ((u16*)outp)[((b * H_ + h) * SEQ + tok) * DH_ + d] = f2bf(y);
                } else if (MODE == 1) {
                    // V tiled: [b*8+h][n/64][d][64]
                    const int d = col & 63, h = col >> 6;
                    const int b = row / SEQ, n = row % SEQ;
                    ((u16*)outp)[(((b * H_ + h) * (N_ / 64) + (n >> 6)) * DH_ + d) * 64 + (n & 63)] = f2bf(v);
                } else {
                    float m = (qmask[row] != 0) ? 1.0f : 0.0f;
                    ((float*)outp)[row * E_ + col] = v * m;
                }
            }
        }
    }
}

// -------------------- fused attention (v3: LDS-staged K/V, double-buffered) --------------------
// grid: 512 wgs (XCD-swizzled), 4 waves. wg = 64 q-rows (wave=16); loop over 32 kv-tiles of 64.
// K tile [64 kv][64 d], V tile [64 d][64 kv] staged via global_load_lds with XOR-swizzled
// source (granule ^= row&7) so ds_read_b128 fragments hit the bank floor.
// Max-free two-pass softmax (scores O(1); masked -> exp underflow 0, matches ref).
__global__ __launch_bounds__(256) void attn_kernel(const u16* __restrict__ qh,
                                                   const u16* __restrict__ kh,
                                                   const u16* __restrict__ vt,
                                                   const int* __restrict__ kv_mask,
                                                   float* __restrict__ attn_out,
                                                   u16* __restrict__ ctx_out) {
    __shared__ __align__(16) u16 kbuf[2][64 * 64];
    __shared__ __align__(16) u16 vbuf[2][64 * 64];
    __shared__ float plds[4][16][68];

    // bijective XCD swizzle: XCD k gets 4 consecutive bh
    const int id = blockIdx.x;
    const int sw = (id & 7) * 64 + (id >> 3);
    const int bh = sw >> 4, qt = sw & 15;
    const int b = bh >> 3, h = bh & 7;
    const int tid = threadIdx.x, w = tid >> 6, lane = tid & 63;
    const int lr = lane & 15, lg = lane >> 4;
    const int q0 = qt * 64 + w * 16;

    const u16* qbase = qh + (bh * QT_ + q0) * DH_;
    const bf16x8 qf0 = ldbf8(qbase + lr * DH_ + lg * 8);
    const bf16x8 qf1 = ldbf8(qbase + lr * DH_ + 32 + lg * 8);
    const u16* kbase = kh + (size_t)bh * (N_ * DH_);           // [N][64]
    const u16* vbase = vt + (size_t)bh * (N_ * DH_);           // [32 tiles][64 d][64]
    const int* mbase = kv_mask + b * N_;

    // stage this wave's 16 rows of an 8KB tile (2 instrs), source pre-swizzled
    auto stage = [&](const u16* gsrc, u16* lbuf) {
#pragma unroll
        for (int i = 0; i < 2; i++) {
            const int r0 = w * 16 + i * 8;
            const int row = r0 + (lane >> 3);
            const u16* src = gsrc + row * 64 + (((lane & 7) ^ (row & 7)) * 8);
            g2lds16(src, lbuf + r0 * 64);
        }
    };

    // ---- pass A: full row sums of exp(score) ----
    float lsum[4] = {0.f, 0.f, 0.f, 0.f};
    stage(kbase, kbuf[0]);
    __syncthreads();
    for (int t = 0; t < 32; t++) {
        const u16* kc = kbuf[t & 1];
        if (t < 31) stage(kbase + (t + 1) * (64 * DH_), kbuf[(t + 1) & 1]);
#pragma unroll
        for (int n = 0; n < 4; n++) {
            const int krow = n * 16 + lr;
            const u16* kp = kc + krow * 64;
            bf16x8 k0 = ldbf8(kp + ((lg ^ (krow & 7)) * 8));
            bf16x8 k1 = ldbf8(kp + (((lg + 4) ^ (krow & 7)) * 8));
            f32x4 c = f32x4{0.f, 0.f, 0.f, 0.f};
            c = MFMA16(qf0, k0, c);
            c = MFMA16(qf1, k1, c);
            const bool keep = (mbase[t * 64 + n * 16 + lr] != 0);
#pragma unroll
            for (int r = 0; r < 4; r++) lsum[r] += keep ? __expf(c[r] * 0.125f) : 0.f;
        }
        __syncthreads();
    }
    float inv[4];
#pragma unroll
    for (int r = 0; r < 4; r++) {
        float s = lsum[r];
        s += __shfl_xor(s, 1); s += __shfl_xor(s, 2);
        s += __shfl_xor(s, 4); s += __shfl_xor(s, 8);
        inv[r] = (s > 0.f) ? (1.0f / s) : 0.f;  // all-masked row -> attn = ctx = 0 (ref)
    }

    // ---- pass B: write attn, accumulate ctx ----
    f32x4 pv[4];
#pragma unroll
    for (int i = 0; i < 4; i++) pv[i] = f32x4{0.f, 0.f, 0.f, 0.f};
    float(*P)[68] = plds[w];
    float* abase = attn_out + ((size_t)(bh * QT_ + q0)) * N_;
    const int srow = lane >> 2, scol = (lane & 3) * 4;

    stage(kbase, kbuf[0]);
    stage(vbase, vbuf[0]);
    __syncthreads();
    for (int t = 0; t < 32; t++) {
        const u16* kc = kbuf[t & 1];
        const u16* vc = vbuf[t & 1];
        if (t < 31) {
            stage(kbase + (t + 1) * (64 * DH_), kbuf[(t + 1) & 1]);
            stage(vbase + (t + 1) * (64 * DH_), vbuf[(t + 1) & 1]);
        }
#pragma unroll
        for (int n = 0; n < 4; n++) {
            const int krow = n * 16 + lr;
            const u16* kp = kc + krow * 64;
            bf16x8 k0 = ldbf8(kp + ((lg ^ (krow & 7)) * 8));
            bf16x8 k1 = ldbf8(kp + (((lg + 4) ^ (krow & 7)) * 8));
            f32x4 c = f32x4{0.f, 0.f, 0.f, 0.f};
            c = MFMA16(qf0, k0, c);
            c = MFMA16(qf1, k1, c);
            const bool keep = (mbase[t * 64 + n * 16 + lr] != 0);
#pragma unroll
            for (int r = 0; r < 4; r++) {
                float p = keep ? (__expf(c[r] * 0.125f) * inv[r]) : 0.f;
                P[lg * 4 + r][n * 16 + lr] = p;
            }
        }
        // coalesced f32x4 attn stores
#pragma unroll
        for (int i = 0; i < 4; i++) {
            f32x4 vv = *reinterpret_cast<const f32x4*>(&P[srow][i * 16 + scol]);
            *reinterpret_cast<f32x4*>(abase + (size_t)srow * N_ + t * 64 + i * 16 + scol) = vv;
        }
        // PV: ctx[16q,64d] += P @ V-tile
#pragma unroll
        for (int ks = 0; ks < 2; ks++) {
            const float* ap = &P[lr][ks * 32 + lg * 8];
            f32x4 a0 = *reinterpret_cast<const f32x4*>(ap);
            f32x4 a1 = *reinterpret_cast<const f32x4*>(ap + 4);
            u16x8 u;
            u[0] = f2bf(a0[0]); u[1] = f2bf(a0[1]); u[2] = f2bf(a0[2]); u[3] = f2bf(a0[3]);
            u[4] = f2bf(a1[0]); u[5] = f2bf(a1[1]); u[6] = f2bf(a1[2]); u[7] = f2bf(a1[3]);
            bf16x8 af = __builtin_bit_cast(bf16x8, u);
#pragma unroll
            for (int nb = 0; nb < 4; nb++) {
                const int vrow = nb * 16 + lr;
                bf16x8 bv = ldbf8(vc + vrow * 64 + (((ks * 4 + lg) ^ (vrow & 7)) * 8));
                pv[nb] = MFMA16(af, bv, pv[nb]);
            }
        }
        __syncthreads();
    }

    // ctx out: [B, QT, H*64] bf16 (feature = h*64+d), feeds O-projection GEMM
#pragma unroll
    for (int nb = 0; nb < 4; nb++) {
#pragma unroll
        for (int r = 0; r < 4; r++) {
            const int row = q0 + lg * 4 + r;
            const int d = nb * 16 + lr;
            ctx_out[((b * QT_ + row) * H_ + h) * DH_ + d] = f2bf(pv[nb][r]);
        }
    }
}

// -------------------- host launch --------------------
extern "C" void kernel_launch(void* const* d_in, const int* in_sizes, int n_in,
                              void* d_out, int out_size, void* d_ws, size_t ws_size,
                              hipStream_t stream) {
    (void)in_sizes; (void)n_in; (void)out_size; (void)ws_size;
    const float* q   = (const float*)d_in[0];
    const float* kv  = (const float*)d_in[1];
    const int* q_mask  = (const int*)d_in[2];
    const int* kv_mask = (const int*)d_in[3];
    const int* q_pos   = (const int*)d_in[4];
    const int* kv_pos  = (const int*)d_in[5];
    const float* Wq = (const float*)d_in[6];  const float* bq = (const float*)d_in[7];
    const float* Wk = (const float*)d_in[8];  const float* bk = (const float*)d_in[9];
    const float* Wv = (const float*)d_in[10]; const float* bv = (const float*)d_in[11];
    const float* Wo = (const float*)d_in[12]; const float* bo = (const float*)d_in[13];
    float* outp = (float*)d_out;

    char* ws = (char*)d_ws;
    size_t off = 0;
    auto carve = [&](size_t bytes) -> void* {
        void* p = ws + off;
        off = (off + bytes + 255) & ~(size_t)255;
        return p;
    };
    u16* qbf   = (u16*)carve((size_t)B_ * QT_ * E_ * 2);
    u16* kvbf  = (u16*)carve((size_t)B_ * N_ * E_ * 2);
    u16* wtq   = (u16*)carve((size_t)E_ * E_ * 2);
    u16* wtk   = (u16*)carve((size_t)E_ * E_ * 2);
    u16* wtv   = (u16*)carve((size_t)E_ * E_ * 2);
    u16* wto   = (u16*)carve((size_t)E_ * E_ * 2);
    u16* qhh   = (u16*)carve((size_t)B_ * H_ * QT_ * DH_ * 2);
    u16* khh   = (u16*)carve((size_t)B_ * H_ * N_ * DH_ * 2);
    u16* vt    = (u16*)carve((size_t)B_ * H_ * DH_ * N_ * 2);  // tiled [bh][32][64][64]
    u16* ctx   = (u16*)carve((size_t)B_ * QT_ * E_ * 2);
    float2* tq = (float2*)carve((size_t)B_ * QT_ * 16 * sizeof(float2));
    float2* tk = (float2*)carve((size_t)B_ * N_ * 16 * sizeof(float2));

    cvt_f32_bf16<<<(B_ * QT_ * E_ / 4) / 256, 256, 0, stream>>>(q, qbf, B_ * QT_ * E_ / 4);
    cvt_f32_bf16<<<(B_ * N_ * E_ / 4) / 256, 256, 0, stream>>>(kv, kvbf, B_ * N_ * E_ / 4);
    w_transpose<<<dim3(8, 8), 256, 0, stream>>>(Wq, wtq);
    w_transpose<<<dim3(8, 8), 256, 0, stream>>>(Wk, wtk);
    w_transpose<<<dim3(8, 8), 256, 0, stream>>>(Wv, wtv);
    w_transpose<<<dim3(8, 8), 256, 0, stream>>>(Wo, wto);
    rope_table<<<(B_ * QT_ * 16) / 256, 256, 0, stream>>>(q_pos, tq, B_ * QT_);
    rope_table<<<(B_ * N_ * 16) / 256, 256, 0, stream>>>(kv_pos, tk, B_ * N_);

    proj_gemm<0, QT_><<<dim3(B_ * QT_ / 64, 8), 256, 0, stream>>>(qbf, wtq, bq, qhh, tq, nullptr);
    proj_gemm<0, N_><<<dim3(B_ * N_ / 64, 8), 256, 0, stream>>>(kvbf, wtk, bk, khh, tk, nullptr);
    proj_gemm<1, N_><<<dim3(B_ * N_ / 64, 8), 256, 0, stream>>>(kvbf, wtv, bv, vt, nullptr, nullptr);

    attn_kernel<<<dim3(512), 256, 0, stream>>>(
        qhh, khh, vt, kv_mask, outp + (size_t)B_ * QT_ * E_, ctx);

    proj_gemm<2, QT_><<<dim3(B_ * QT_ / 64, 8), 256, 0, stream>>>(ctx, wto, bo, outp, nullptr, q_mask);
}

// Round 4
// 193.599 us; speedup vs baseline: 1.6807x; 1.2878x over previous
//
#include <hip/hip_runtime.h>
#include <hip/hip_bf16.h>

// Problem constants (CrossEncoder): B=4, QT=1024, N=2048, E=512, H=8, Dh=64
#define B_  4
#define QT_ 1024
#define N_  2048
#define E_  512
#define H_  8
#define DH_ 64

typedef float  f32x4  __attribute__((ext_vector_type(4)));
typedef __bf16 bf16x8 __attribute__((ext_vector_type(8)));
typedef unsigned short u16;
typedef u16 u16x8 __attribute__((ext_vector_type(8)));
typedef u16 u16x4 __attribute__((ext_vector_type(4)));

// round-to-nearest-even f32 -> bf16
static __device__ __forceinline__ u16 f2bf(float f) {
    unsigned u = __builtin_bit_cast(unsigned, f);
    return (u16)((u + 0x7fffu + ((u >> 16) & 1u)) >> 16);
}

static __device__ __forceinline__ bf16x8 ldbf8(const u16* p) {
    uint4 v = *reinterpret_cast<const uint4*>(p);
    return __builtin_bit_cast(bf16x8, v);
}

#define MFMA16(a, b, c) __builtin_amdgcn_mfma_f32_16x16x32_bf16((a), (b), (c), 0, 0, 0)

// async global->LDS, 16B per lane; LDS dest = uniform base + lane*16 (linear)
static __device__ __forceinline__ void g2lds16(const u16* g, u16* l) {
    __builtin_amdgcn_global_load_lds((__attribute__((address_space(1))) void*)(void*)g,
                                     (__attribute__((address_space(3))) void*)l, 16, 0, 0);
}

// -------------------- f32 -> bf16 convert (vectorized) --------------------
__global__ __launch_bounds__(256) void cvt_f32_bf16(const float* __restrict__ s,
                                                    u16* __restrict__ d, int n4) {
    int i = blockIdx.x * 256 + threadIdx.x;
    if (i >= n4) return;
    float4 v = reinterpret_cast<const float4*>(s)[i];
    ushort4 o;
    o.x = f2bf(v.x); o.y = f2bf(v.y); o.z = f2bf(v.z); o.w = f2bf(v.w);
    reinterpret_cast<ushort4*>(d)[i] = o;
}

// -------------------- weight transpose + convert: Wt[n][k] = bf16(W[k][n]) --------------------
__global__ __launch_bounds__(256) void w_transpose(const float* __restrict__ W,
                                                   u16* __restrict__ Wt) {
    __shared__ float t[64][65];
    int k0 = blockIdx.x * 64, n0 = blockIdx.y * 64;
    int tid = threadIdx.x;
#pragma unroll
    for (int i = 0; i < 16; i++) {
        int idx = tid + i * 256, r = idx >> 6, c = idx & 63;
        t[r][c] = W[(k0 + r) * E_ + n0 + c];
    }
    __syncthreads();
#pragma unroll
    for (int i = 0; i < 16; i++) {
        int idx = tid + i * 256, r = idx >> 6, c = idx & 63;
        Wt[(n0 + r) * E_ + k0 + c] = f2bf(t[c][r]);
    }
}

// -------------------- RoPE table (reference quirk: freq index = d>>2, 16 freqs) ----------
__global__ __launch_bounds__(256) void rope_table(const int* __restrict__ pos,
                                                  float2* __restrict__ tab, int rows) {
    int i = blockIdx.x * 256 + threadIdx.x;
    if (i >= rows * 16) return;
    int k = i & 15, row = i >> 4;
    float fr = exp2f((float)k * -0.41524101186092028f);  // log2(10000)/32
    float ang = (float)pos[row] * fr;
    float sn, cs;
    sincosf(ang, &sn, &cs);
    tab[i] = make_float2(cs, sn);
}

// -------------------- staged projection GEMM (m97 structure) --------------------
// 128x128 tile, BK=64, double-buffered LDS via global_load_lds(16B) w/ pre-swizzled src.
// 4 waves, each 64x64 (4x4 16x16x32 acc). XCD-swizzled 1D grid: XCD k owns a contiguous
// M-stripe (A+B per XCD ~2MB, L2-resident).
// MODE 0: Q  -> RoPE epilogue, bf16 head layout [B,H,SEQ,64]
// MODE 1: KV -> n0<512: K (RoPE, head layout); n0>=512: V (tiled [bh][n/64][d][64])
// MODE 2: O  -> f32 row-major * q_mask (into d_out)
template <int MODE, int SEQ, int XB>
__global__ __launch_bounds__(256) void proj_staged(const u16* __restrict__ X,
                                                   const u16* __restrict__ Wt,
                                                   const float* __restrict__ bias0,
                                                   const float* __restrict__ bias1,
                                                   void* __restrict__ out0,
                                                   u16* __restrict__ out1,
                                                   const float2* __restrict__ rope_tab,
                                                   const int* __restrict__ qmask) {
    __shared__ __align__(16) u16 la[2][128 * 64];
    __shared__ __align__(16) u16 lb[2][128 * 64];

    // bijective XCD swizzle: XCD k gets x in [k*xs, k*xs+xs), all y
    constexpr int xs = XB / 8;
    const int id = blockIdx.x;
    const int xcd = id & 7, l = id >> 3;
    const int m0 = (xs * xcd + (l % xs)) * 128;
    const int n0 = (l / xs) * 128;

    const int tid = threadIdx.x;
    const int w = tid >> 6, lane = tid & 63;
    const int lr = lane & 15, lg = lane >> 4;
    const int wml = (w >> 1) * 64, wnl = (w & 1) * 64;

    // stage: wave w stages rows [w*32, w*32+32) of a 128x64 tile (4 instrs), src pre-swizzled
    auto stage = [&](const u16* gsrc, int gstride, u16* lbuf) {
#pragma unroll
        for (int i = 0; i < 4; i++) {
            const int r0 = w * 32 + i * 8;
            const int row = r0 + (lane >> 3);
            const u16* src = gsrc + row * gstride + (((lane & 7) ^ (row & 7)) * 8);
            g2lds16(src, lbuf + r0 * 64);
        }
    };

    f32x4 acc[4][4];
#pragma unroll
    for (int i = 0; i < 4; i++)
#pragma unroll
        for (int j = 0; j < 4; j++) acc[i][j] = f32x4{0.f, 0.f, 0.f, 0.f};

    stage(X + m0 * E_, E_, la[0]);
    stage(Wt + n0 * E_, E_, lb[0]);
    __syncthreads();
    int buf = 0;
    for (int kt = 0; kt < E_ / 64; kt++) {
        if (kt + 1 < E_ / 64) {
            stage(X + m0 * E_ + (kt + 1) * 64, E_, la[buf ^ 1]);
            stage(Wt + n0 * E_ + (kt + 1) * 64, E_, lb[buf ^ 1]);
        }
#pragma unroll
        for (int ks = 0; ks < 2; ks++) {
            bf16x8 a[4], bb[4];
#pragma unroll
            for (int mb = 0; mb < 4; mb++) {
                const int r = wml + mb * 16 + lr;
                a[mb] = ldbf8(la[buf] + r * 64 + (((ks * 4 + lg) ^ (r & 7)) * 8));
            }
#pragma unroll
            for (int nb = 0; nb < 4; nb++) {
                const int r = wnl + nb * 16 + lr;
                bb[nb] = ldbf8(lb[buf] + r * 64 + (((ks * 4 + lg) ^ (r & 7)) * 8));
            }
            __builtin_amdgcn_s_setprio(1);
#pragma unroll
            for (int mb = 0; mb < 4; mb++)
#pragma unroll
                for (int nb = 0; nb < 4; nb++)
                    acc[mb][nb] = MFMA16(a[mb], bb[nb], acc[mb][nb]);
            __builtin_amdgcn_s_setprio(0);
        }
        __syncthreads();
        buf ^= 1;
    }

    const bool isV = (MODE == 1) && (n0 >= 512);
#pragma unroll
    for (int mb = 0; mb < 4; mb++) {
#pragma unroll
        for (int nb = 0; nb < 4; nb++) {
            const int col = n0 + wnl + nb * 16 + lr;     // C col = lane&15
            const float bs = isV ? bias1[col - 512] : bias0[col];
#pragma unroll
            for (int r = 0; r < 4; r++) {
                const int row = m0 + wml + mb * 16 + lg * 4 + r;  // C row = (lane>>4)*4+reg
                float v = acc[mb][nb][r] + bs;
                if (MODE == 2) {
                    float m = (qmask[row] != 0) ? 1.0f : 0.0f;
                    ((float*)out0)[row * E_ + col] = v * m;
                } else if (isV) {
                    const int cv = col - 512;
                    const int d = cv & 63, h = cv >> 6;
                    const int b = row / SEQ, n = row % SEQ;
                    out1[(((b * H_ + h) * (N_ / 64) + (n >> 6)) * DH_ + d) * 64 + (n & 63)] = f2bf(v);
                } else {
                    // Q or K: RoPE + head layout
                    const int d = col & 63, h = col >> 6;
                    float2 t = rope_tab[row * 16 + (d >> 2)];
                    float other = __shfl_xor(v, 1);  // pair mate: col^1 lives in lane^1
                    float y = (d & 1) ? (other * t.y + v * t.x) : (v * t.x - other * t.y);
                    const int b = row / SEQ, tok = row % SEQ;
                    ((u16*)out0)[((b * H_ + h) * SEQ + tok) * DH_ + d] = f2bf(y);
                }
            }
        }
    }
}

// -------------------- fused attention (LDS-staged K/V, double-buffered) --------------------
// grid: 512 wgs (XCD-swizzled), 4 waves. wg = 64 q-rows (wave=16); loop over 32 kv-tiles.
// Max-free two-pass softmax (scores O(1); masked -> exp underflow 0, matches ref).
__global__ __launch_bounds__(256) void attn_kernel(const u16* __restrict__ qh,
                                                   const u16* __restrict__ kh,
                                                   const u16* __restrict__ vt,
                                                   const int* __restrict__ kv_mask,
                                                   float* __restrict__ attn_out,
                                                   u16* __restrict__ ctx_out) {
    __shared__ __align__(16) u16 kbuf[2][64 * 64];
    __shared__ __align__(16) u16 vbuf[2][64 * 64];
    __shared__ float plds[4][16][68];

    // bijective XCD swizzle: XCD k gets 4 consecutive bh
    const int id = blockIdx.x;
    const int sw = (id & 7) * 64 + (id >> 3);
    const int bh = sw >> 4, qt = sw & 15;
    const int b = bh >> 3, h = bh & 7;
    const int tid = threadIdx.x, w = tid >> 6, lane = tid & 63;
    const int lr = lane & 15, lg = lane >> 4;
    const int q0 = qt * 64 + w * 16;

    const u16* qbase = qh + (bh * QT_ + q0) * DH_;
    const bf16x8 qf0 = ldbf8(qbase + lr * DH_ + lg * 8);
    const bf16x8 qf1 = ldbf8(qbase + lr * DH_ + 32 + lg * 8);
    const u16* kbase = kh + (size_t)bh * (N_ * DH_);           // [N][64]
    const u16* vbase = vt + (size_t)bh * (N_ * DH_);           // [32 tiles][64 d][64]
    const int* mbase = kv_mask + b * N_;

    // stage this wave's 16 rows of an 8KB tile (2 instrs), source pre-swizzled
    auto stage = [&](const u16* gsrc, u16* lbuf) {
#pragma unroll
        for (int i = 0; i < 2; i++) {
            const int r0 = w * 16 + i * 8;
            const int row = r0 + (lane >> 3);
            const u16* src = gsrc + row * 64 + (((lane & 7) ^ (row & 7)) * 8);
            g2lds16(src, lbuf + r0 * 64);
        }
    };

    // ---- pass A: full row sums of exp(score) ----
    float lsum[4] = {0.f, 0.f, 0.f, 0.f};
    stage(kbase, kbuf[0]);
    __syncthreads();
    for (int t = 0; t < 32; t++) {
        const u16* kc = kbuf[t & 1];
        if (t < 31) stage(kbase + (t + 1) * (64 * DH_), kbuf[(t + 1) & 1]);
#pragma unroll
        for (int n = 0; n < 4; n++) {
            const int krow = n * 16 + lr;
            const u16* kp = kc + krow * 64;
            bf16x8 k0 = ldbf8(kp + ((lg ^ (krow & 7)) * 8));
            bf16x8 k1 = ldbf8(kp + (((lg + 4) ^ (krow & 7)) * 8));
            f32x4 c = f32x4{0.f, 0.f, 0.f, 0.f};
            __builtin_amdgcn_s_setprio(1);
            c = MFMA16(qf0, k0, c);
            c = MFMA16(qf1, k1, c);
            __builtin_amdgcn_s_setprio(0);
            const bool keep = (mbase[t * 64 + n * 16 + lr] != 0);
#pragma unroll
            for (int r = 0; r < 4; r++) lsum[r] += keep ? __expf(c[r] * 0.125f) : 0.f;
        }
        __syncthreads();
    }
    float inv[4];
#pragma unroll
    for (int r = 0; r < 4; r++) {
        float s = lsum[r];
        s += __shfl_xor(s, 1); s += __shfl_xor(s, 2);
        s += __shfl_xor(s, 4); s += __shfl_xor(s, 8);
        inv[r] = (s > 0.f) ? (1.0f / s) : 0.f;  // all-masked row -> attn = ctx = 0 (ref)
    }

    // ---- pass B: write attn, accumulate ctx ----
    f32x4 pv[4];
#pragma unroll
    for (int i = 0; i < 4; i++) pv[i] = f32x4{0.f, 0.f, 0.f, 0.f};
    float(*P)[68] = plds[w];
    float* abase = attn_out + ((size_t)(bh * QT_ + q0)) * N_;
    const int srow = lane >> 4, scol = (lane & 15) * 4;  // 4 rows x 256B per store instr

    stage(kbase, kbuf[0]);
    stage(vbase, vbuf[0]);
    __syncthreads();
    for (int t = 0; t < 32; t++) {
        const u16* kc = kbuf[t & 1];
        const u16* vc = vbuf[t & 1];
        if (t < 31) {
            stage(kbase + (t + 1) * (64 * DH_), kbuf[(t + 1) & 1]);
            stage(vbase + (t + 1) * (64 * DH_), vbuf[(t + 1) & 1]);
        }
#pragma unroll
        for (int n = 0; n < 4; n++) {
            const int krow = n * 16 + lr;
            const u16* kp = kc + krow * 64;
            bf16x8 k0 = ldbf8(kp + ((lg ^ (krow & 7)) * 8));
            bf16x8 k1 = ldbf8(kp + (((lg + 4) ^ (krow & 7)) * 8));
            f32x4 c = f32x4{0.f, 0.f, 0.f, 0.f};
            __builtin_amdgcn_s_setprio(1);
            c = MFMA16(qf0, k0, c);
            c = MFMA16(qf1, k1, c);
            __builtin_amdgcn_s_setprio(0);
            const bool keep = (mbase[t * 64 + n * 16 + lr] != 0);
#pragma unroll
            for (int r = 0; r < 4; r++) {
                float p = keep ? (__expf(c[r] * 0.125f) * inv[r]) : 0.f;
                P[lg * 4 + r][n * 16 + lr] = p;
            }
        }
        // coalesced attn stores: each instr = 4 rows x 256B contiguous
#pragma unroll
        for (int i = 0; i < 4; i++) {
            const int row = i * 4 + srow;
            f32x4 vv = *reinterpret_cast<const f32x4*>(&P[row][scol]);
            *reinterpret_cast<f32x4*>(abase + (size_t)row * N_ + t * 64 + scol) = vv;
        }
        // PV: ctx[16q,64d] += P @ V-tile
#pragma unroll
        for (int ks = 0; ks < 2; ks++) {
            const float* ap = &P[lr][ks * 32 + lg * 8];
            f32x4 a0 = *reinterpret_cast<const f32x4*>(ap);
            f32x4 a1 = *reinterpret_cast<const f32x4*>(ap + 4);
            u16x8 u;
            u[0] = f2bf(a0[0]); u[1] = f2bf(a0[1]); u[2] = f2bf(a0[2]); u[3] = f2bf(a0[3]);
            u[4] = f2bf(a1[0]); u[5] = f2bf(a1[1]); u[6] = f2bf(a1[2]); u[7] = f2bf(a1[3]);
            bf16x8 af = __builtin_bit_cast(bf16x8, u);
            __builtin_amdgcn_s_setprio(1);
#pragma unroll
            for (int nb = 0; nb < 4; nb++) {
                const int vrow = nb * 16 + lr;
                bf16x8 bv = ldbf8(vc + vrow * 64 + (((ks * 4 + lg) ^ (vrow & 7)) * 8));
                pv[nb] = MFMA16(af, bv, pv[nb]);
            }
            __builtin_amdgcn_s_setprio(0);
        }
        __syncthreads();
    }

    // ctx out: [B, QT, H*64] bf16 (feature = h*64+d), feeds O-projection GEMM
#pragma unroll
    for (int nb = 0; nb < 4; nb++) {
#pragma unroll
        for (int r = 0; r < 4; r++) {
            const int row = q0 + lg * 4 + r;
            const int d = nb * 16 + lr;
            ctx_out[((b * QT_ + row) * H_ + h) * DH_ + d] = f2bf(pv[nb][r]);
        }
    }
}

// -------------------- host launch --------------------
extern "C" void kernel_launch(void* const* d_in, const int* in_sizes, int n_in,
                              void* d_out, int out_size, void* d_ws, size_t ws_size,
                              hipStream_t stream) {
    (void)in_sizes; (void)n_in; (void)out_size; (void)ws_size;
    const float* q   = (const float*)d_in[0];
    const float* kv  = (const float*)d_in[1];
    const int* q_mask  = (const int*)d_in[2];
    const int* kv_mask = (const int*)d_in[3];
    const int* q_pos   = (const int*)d_in[4];
    const int* kv_pos  = (const int*)d_in[5];
    const float* Wq = (const float*)d_in[6];  const float* bq = (const float*)d_in[7];
    const float* Wk = (const float*)d_in[8];  const float* bk = (const float*)d_in[9];
    const float* Wv = (const float*)d_in[10]; const float* bv = (const float*)d_in[11];
    const float* Wo = (const float*)d_in[12]; const float* bo = (const float*)d_in[13];
    float* outp = (float*)d_out;

    char* ws = (char*)d_ws;
    size_t off = 0;
    auto carve = [&](size_t bytes) -> void* {
        void* p = ws + off;
        off = (off + bytes + 255) & ~(size_t)255;
        return p;
    };
    u16* qbf   = (u16*)carve((size_t)B_ * QT_ * E_ * 2);
    u16* kvbf  = (u16*)carve((size_t)B_ * N_ * E_ * 2);
    u16* wtq   = (u16*)carve((size_t)E_ * E_ * 2);
    u16* wtkv  = (u16*)carve((size_t)2 * E_ * E_ * 2);   // [1024][512]: rows 0-511 K^T, 512-1023 V^T
    u16* wto   = (u16*)carve((size_t)E_ * E_ * 2);
    u16* qhh   = (u16*)carve((size_t)B_ * H_ * QT_ * DH_ * 2);
    u16* khh   = (u16*)carve((size_t)B_ * H_ * N_ * DH_ * 2);
    u16* vt    = (u16*)carve((size_t)B_ * H_ * DH_ * N_ * 2);  // tiled [bh][32][64][64]
    u16* ctx   = (u16*)carve((size_t)B_ * QT_ * E_ * 2);
    float2* tq = (float2*)carve((size_t)B_ * QT_ * 16 * sizeof(float2));
    float2* tk = (float2*)carve((size_t)B_ * N_ * 16 * sizeof(float2));

    cvt_f32_bf16<<<(B_ * QT_ * E_ / 4) / 256, 256, 0, stream>>>(q, qbf, B_ * QT_ * E_ / 4);
    cvt_f32_bf16<<<(B_ * N_ * E_ / 4) / 256, 256, 0, stream>>>(kv, kvbf, B_ * N_ * E_ / 4);
    w_transpose<<<dim3(8, 8), 256, 0, stream>>>(Wq, wtq);
    w_transpose<<<dim3(8, 8), 256, 0, stream>>>(Wk, wtkv);
    w_transpose<<<dim3(8, 8), 256, 0, stream>>>(Wv, wtkv + 512 * 512);
    w_transpose<<<dim3(8, 8), 256, 0, stream>>>(Wo, wto);
    rope_table<<<(B_ * QT_ * 16) / 256, 256, 0, stream>>>(q_pos, tq, B_ * QT_);
    rope_table<<<(B_ * N_ * 16) / 256, 256, 0, stream>>>(kv_pos, tk, B_ * N_);

    // Q: M=4096, N=512 -> grid 32x4 = 128
    proj_staged<0, QT_, 32><<<dim3(128), 256, 0, stream>>>(qbf, wtq, bq, nullptr, qhh, nullptr, tq, nullptr);
    // KV fused: M=8192, N=1024 -> grid 64x8 = 512
    proj_staged<1, N_, 64><<<dim3(512), 256, 0, stream>>>(kvbf, wtkv, bk, bv, khh, vt, tk, nullptr);

    attn_kernel<<<dim3(512), 256, 0, stream>>>(
        qhh, khh, vt, kv_mask, outp + (size_t)B_ * QT_ * E_, ctx);

    // O: M=4096, N=512 -> grid 128
    proj_staged<2, QT_, 32><<<dim3(128), 256, 0, stream>>>(ctx, wto, bo, nullptr, outp, nullptr, nullptr, q_mask);
}